// Round 11
// baseline (449.547 us; speedup 1.0000x reference)
//
#include <hip/hip_runtime.h>
#include <cmath>

#define SCALE_F 0.088388347648318447f  // 1/sqrt(128)

typedef _Float16 f16;
typedef _Float16 f16x8 __attribute__((ext_vector_type(8)));
typedef _Float16 f16x4 __attribute__((ext_vector_type(4)));
typedef __fp16 fp16x2 __attribute__((ext_vector_type(2)));
typedef float f32x4 __attribute__((ext_vector_type(4)));
typedef float f32x16 __attribute__((ext_vector_type(16)));
typedef unsigned int u32;
typedef unsigned int u32x2 __attribute__((ext_vector_type(2)));
typedef unsigned int u32x4 __attribute__((ext_vector_type(4)));

#define MFMA16(a, b, c) __builtin_amdgcn_mfma_f32_16x16x32_f16(a, b, c, 0, 0, 0)
#define MFMA32(a, b, c) __builtin_amdgcn_mfma_f32_32x32x16_f16(a, b, c, 0, 0, 0)
#define Z16 ((f32x16){0.f,0.f,0.f,0.f,0.f,0.f,0.f,0.f,0.f,0.f,0.f,0.f,0.f,0.f,0.f,0.f})
#define EX2(x) __builtin_amdgcn_exp2f(x)

__device__ __forceinline__ void gl2lds16(const f16* g, f16* l) {
    __builtin_amdgcn_global_load_lds(
        (const __attribute__((address_space(1))) unsigned int*)g,
        (__attribute__((address_space(3))) unsigned int*)l, 16, 0, 0);
}

// packed RTZ convert: 1 instruction for 2 values (P in [0, 2^8] -> bias ~ -0.5ulp, ok)
__device__ __forceinline__ u32 pkz(float x, float y) {
    fp16x2 h = __builtin_amdgcn_cvt_pkrtz(x, y);
    return __builtin_bit_cast(u32, h);
}
// own + partner(lane^32): explicit fresh register (=&v) so operands can't coalesce;
// symmetric combine -> correct under either permlane32_swap direction.
__device__ __forceinline__ float fswapsum(float x) {
    u32 a = __builtin_bit_cast(u32, x), b;
    asm volatile("v_mov_b32 %0, %1" : "=&v"(b) : "v"(a));
    asm volatile("v_permlane32_swap_b32 %0, %1" : "+v"(a), "+v"(b));
    return __builtin_bit_cast(float, a) + __builtin_bit_cast(float, b);
}
__device__ __forceinline__ float fswapmax(float x) {
    u32 a = __builtin_bit_cast(u32, x), b;
    asm volatile("v_mov_b32 %0, %1" : "=&v"(b) : "v"(a));
    asm volatile("v_permlane32_swap_b32 %0, %1" : "+v"(a), "+v"(b));
    return fmaxf(__builtin_bit_cast(float, a), __builtin_bit_cast(float, b));
}
#define MAX3(a, b, c) fmaxf(fmaxf((a), (b)), (c))   // fuses to v_max3_f32

// ---------------- merged f32 -> f16 convert for all 6 inputs ----------------
__global__ __launch_bounds__(256) void cvt_all(
    const float* __restrict__ hs, const float* __restrict__ es,
    const float* __restrict__ Wq, const float* __restrict__ Wk,
    const float* __restrict__ Wv, const float* __restrict__ Wo,
    f16* __restrict__ dst)
{
    const int c = blockIdx.x * 256 + threadIdx.x;   // chunk of 8 f32, 4194304 total
    const float* src; int off;
    if (c < 2097152) { src = (c < 1048576) ? hs : es; off = c & 1048575; }
    else {
        const int cc = c - 2097152;
        const int wsel = cc >> 19; off = cc & 524287;
        src = wsel == 0 ? Wq : wsel == 1 ? Wk : wsel == 2 ? Wv : Wo;
    }
    const float4* p = (const float4*)src + (size_t)off * 2;
    const float4 a = p[0], b2 = p[1];
    f16x8 o = {(f16)a.x, (f16)a.y, (f16)a.z, (f16)a.w,
               (f16)b2.x, (f16)b2.y, (f16)b2.z, (f16)b2.w};
    *(f16x8*)(dst + (size_t)c * 8) = o;
}

// ---------------- GEMM: C[M,N] = A[M,K] @ W[N,K]^T, fp16 in, MFMA ----------------
// OUT_MODE: 0 = f16 [M][N]
//           2 = f32 [M][N]
//           3 = f16 "Vt" write: out[((c>>11)*2048 + r)*2048 + (c&2047)]  (A=Wv, W=es)
//           4 = f16 [M][N] with fused RoPE (pairs along c; tables Cs/Sn [2048][64])
template <int OUT_MODE>
__global__ __launch_bounds__(256, 2) void gemm16(
    const f16* __restrict__ A, const f16* __restrict__ W,
    void* __restrict__ Cv, int M, int N, int K,
    const float* __restrict__ Cs, const float* __restrict__ Sn)
{
    __shared__ __align__(16) f16 Al[128 * 64];
    __shared__ __align__(16) f16 Bl[128 * 64];
    const int tid = threadIdx.x;
    const int l = tid & 63, w = tid >> 6;
    const int wr = w >> 1, wc = w & 1;

    const int nwg = gridDim.x, cpx = nwg >> 3;
    const int bid = blockIdx.x;
    const int swz = (bid & 7) * cpx + (bid >> 3);
    const int nbn = N >> 7;
    const int bm = (swz / nbn) * 128, bn = (swz % nbn) * 128;

    f32x4 acc[4][4];
#pragma unroll
    for (int i = 0; i < 4; ++i)
#pragma unroll
        for (int j = 0; j < 4; ++j) acc[i][j] = (f32x4){0.f, 0.f, 0.f, 0.f};

    const int srow = tid >> 3;
    const int sg = tid & 7;

    for (int k0 = 0; k0 < K; k0 += 64) {
        __syncthreads();
#pragma unroll
        for (int i = 0; i < 4; ++i) {
            const int row = i * 32 + srow;
            const int lg = sg ^ (row & 7);
            gl2lds16(A + (size_t)(bm + row) * K + k0 + lg * 8, Al + row * 64 + sg * 8);
            gl2lds16(W + (size_t)(bn + row) * K + k0 + lg * 8, Bl + row * 64 + sg * 8);
        }
        __syncthreads();
#pragma unroll
        for (int kk = 0; kk < 2; ++kk) {
            f16x8 a[4], b[4];
            const int g = kk * 4 + (l >> 4);
#pragma unroll
            for (int m = 0; m < 4; ++m) {
                const int row = wr * 64 + m * 16 + (l & 15);
                a[m] = *(const f16x8*)(Al + row * 64 + (g ^ (row & 7)) * 8);
            }
#pragma unroll
            for (int n = 0; n < 4; ++n) {
                const int row = wc * 64 + n * 16 + (l & 15);
                b[n] = *(const f16x8*)(Bl + row * 64 + (g ^ (row & 7)) * 8);
            }
#pragma unroll
            for (int m = 0; m < 4; ++m)
#pragma unroll
                for (int n = 0; n < 4; ++n)
                    acc[m][n] = MFMA16(a[m], b[n], acc[m][n]);
        }
    }

#pragma unroll
    for (int m = 0; m < 4; ++m)
#pragma unroll
        for (int n = 0; n < 4; ++n)
#pragma unroll
            for (int j = 0; j < 4; ++j) {
                const int r = bm + wr * 64 + m * 16 + ((l >> 4) << 2) + j;
                const int c = bn + wc * 64 + n * 16 + (l & 15);
                if (OUT_MODE == 0) {
                    ((f16*)Cv)[(size_t)r * N + c] = (f16)acc[m][n][j];
                } else if (OUT_MODE == 2) {
                    ((float*)Cv)[(size_t)r * N + c] = acc[m][n][j];
                } else if (OUT_MODE == 3) {
                    ((f16*)Cv)[(size_t)((c >> 11) * 2048 + r) * 2048 + (c & 2047)] = (f16)acc[m][n][j];
                } else if (OUT_MODE == 4) {
                    const float v = acc[m][n][j];
                    const float vp = __shfl_xor(v, 1);
                    const int t = r & 2047;
                    const int i2 = (c & 127) >> 1;
                    const float co = Cs[t * 64 + i2];
                    const float si = Sn[t * 64 + i2];
                    const float y = (c & 1) ? fmaf(v, co, vp * si) : fmaf(v, co, -vp * si);
                    ((f16*)Cv)[(size_t)r * N + c] = (f16)y;
                }
            }
}

// ---------------- Flash attention: 4 waves x 32 q-rows, 32x32x16 MFMA, swapped QK^T ----------------
// SINGLE-buffer padded LDS (35 KB -> 4 blocks/CU, occupancy 2x). Reg-staged K/V (T14:
// loads issued before QK^T, writes after the read barrier). K pitch 132 / V pitch 68 halfs
// -> 2-words/row bank rotation -> ds reads ~2-way (free). cvt_pkrtz pack, max3 trees.
__global__ __launch_bounds__(256, 4) void attn16(
    const f16* __restrict__ Qg, const f16* __restrict__ Kg,
    const f16* __restrict__ Vt, f16* __restrict__ Og)
{
    __shared__ __align__(16) f16 Kl[64 * 132];   // [s][d], pitch 132 (264B)
    __shared__ __align__(16) f16 Vl[128 * 68];   // [d][s], pitch 68  (136B)
    __shared__ float bnc[4][32];                 // per-wave q-indexed broadcast

    const int tid = threadIdx.x;
    const int l = tid & 63, w = tid >> 6;           // w in 0..3
    const int l31 = l & 31, hi = l >> 5;
    const int hi4 = hi * 4;

    // staging decomposition
    const int krow = tid >> 4, kg = tid & 15;       // K: rows krow+16u, granule kg (16B)
    const int vd = tid >> 3, vg = tid & 7;          // V: d-rows vd+32u, granule vg

    // XCD swizzle: 512 blocks, 64 consecutive per XCD
    const int bid = blockIdx.x;
    const int swz = (bid & 7) * 64 + (bid >> 3);
    const int bh = swz >> 4, qt = swz & 15;
    const int b = bh >> 4, h = bh & 15;

    // Q fragments (B-operand): lane's q = l31; k = kc*16 + hi*8 + e. Scale folded (log2e).
    const int qrow = b * 2048 + qt * 128 + w * 32 + l31;
    const f16 qsc = (f16)(0.088388347648318447f * 1.44269504088896f);
    f16x8 qf[8];
#pragma unroll
    for (int kc = 0; kc < 8; ++kc) {
        f16x8 t0 = *(const f16x8*)(Qg + (size_t)qrow * 2048 + h * 128 + kc * 16 + hi * 8);
#pragma unroll
        for (int e = 0; e < 8; ++e) t0[e] = t0[e] * qsc;
        qf[kc] = t0;
    }

    f32x16 o[4] = {Z16, Z16, Z16, Z16};   // O[q=crow(r,hi)][d=dt*32+l31]
    float mrow = -3.0e38f, lrow = 0.0f;   // per-lane, q = l31 (dup across hi)

    const f16* Kbase = Kg + (size_t)(b * 2048) * 2048 + h * 128;
    const f16* Vbase = Vt + (size_t)(b * 2048 + h * 128) * 2048;

    u32x4 kst[4], vst[4];

#define LOADT(st) do {                                                                   \
    _Pragma("unroll")                                                                    \
    for (int u = 0; u < 4; ++u)                                                          \
        kst[u] = *(const u32x4*)(Kbase + (size_t)((st) + krow + u * 16) * 2048 + kg * 8);\
    _Pragma("unroll")                                                                    \
    for (int u = 0; u < 4; ++u)                                                          \
        vst[u] = *(const u32x4*)(Vbase + (size_t)(vd + u * 32) * 2048 + (st) + vg * 8);  \
} while (0)

#define WRITET() do {                                                                    \
    _Pragma("unroll")                                                                    \
    for (int u = 0; u < 4; ++u) {                                                        \
        f16* p = &Kl[(krow + u * 16) * 132 + kg * 8];                                    \
        *(u32x2*)p       = (u32x2){kst[u].x, kst[u].y};                                  \
        *(u32x2*)(p + 4) = (u32x2){kst[u].z, kst[u].w};                                  \
    }                                                                                    \
    _Pragma("unroll")                                                                    \
    for (int u = 0; u < 4; ++u) {                                                        \
        f16* p = &Vl[(vd + u * 32) * 68 + vg * 8];                                       \
        *(u32x2*)p       = (u32x2){vst[u].x, vst[u].y};                                  \
        *(u32x2*)(p + 4) = (u32x2){vst[u].z, vst[u].w};                                  \
    }                                                                                    \
} while (0)

    LOADT(0);
    WRITET();
    __syncthreads();

    for (int t = 0; t < 32; ++t) {
        if (t < 31) LOADT((t + 1) * 64);            // issue early: hides under compute

        // ---- QK^T (swapped): P^T[s][q], lane holds q=l31, s = (r&3)+8*(r>>2)+4*hi (+32 for p1)
        f32x16 p0 = Z16, p1 = Z16;
        __builtin_amdgcn_s_setprio(1);
#pragma unroll
        for (int kc = 0; kc < 8; ++kc) {
            const int go = (kc * 2 + hi) * 8;
            const f16* kp0 = Kl + l31 * 132 + go;
            const f16* kp1 = Kl + (32 + l31) * 132 + go;
            const f16x4 a0 = *(const f16x4*)kp0, a1 = *(const f16x4*)(kp0 + 4);
            const f16x4 b0 = *(const f16x4*)kp1, b1 = *(const f16x4*)(kp1 + 4);
            const f16x8 k0 = __builtin_shufflevector(a0, a1, 0, 1, 2, 3, 4, 5, 6, 7);
            const f16x8 k1 = __builtin_shufflevector(b0, b1, 0, 1, 2, 3, 4, 5, 6, 7);
            p0 = MFMA32(k0, qf[kc], p0);
            p1 = MFMA32(k1, qf[kc], p1);
        }
        __builtin_amdgcn_s_setprio(0);

        // ---- online softmax (log2 domain): max3 reduction, lane-pair combine
        float pp[32];
#pragma unroll
        for (int r = 0; r < 16; ++r) { pp[r] = p0[r]; pp[16 + r] = p1[r]; }
        float mv[11];
#pragma unroll
        for (int i = 0; i < 10; ++i) mv[i] = MAX3(pp[3 * i], pp[3 * i + 1], pp[3 * i + 2]);
        mv[10] = fmaxf(pp[30], pp[31]);
        const float n0 = MAX3(mv[0], mv[1], mv[2]);
        const float n1 = MAX3(mv[3], mv[4], mv[5]);
        const float n2 = MAX3(mv[6], mv[7], mv[8]);
        const float n3 = MAX3(mv[9], mv[10], n0);
        float mx = MAX3(n1, n2, n3);
        mx = fswapmax(mx);

        if (!__all(mx <= mrow + 8.0f)) {
            const float mn = fmaxf(mrow, mx);
            const float cr = EX2(mrow - mn);
            mrow = mn;
            lrow *= cr;
            if (hi == 0) bnc[w][l31] = cr;
#pragma unroll
            for (int r = 0; r < 16; ++r) {
                const float crr = bnc[w][(r & 3) + 8 * (r >> 2) + 4 * hi];
                o[0][r] *= crr; o[1][r] *= crr; o[2][r] *= crr; o[3][r] *= crr;
            }
        }

        // exp2 (1 v_exp_f32 each) + depth-5 sum tree
        float st16[16];
#pragma unroll
        for (int r = 0; r < 16; ++r) {
            p0[r] = EX2(p0[r] - mrow);
            p1[r] = EX2(p1[r] - mrow);
            st16[r] = p0[r] + p1[r];
        }
#pragma unroll
        for (int r = 0; r < 8; ++r) st16[r] += st16[r + 8];
#pragma unroll
        for (int r = 0; r < 4; ++r) st16[r] += st16[r + 4];
        lrow += fswapsum((st16[0] + st16[1]) + (st16[2] + st16[3]));

        // ---- pack P -> A-frags from OWN lane values only (cvt_pkrtz, no cross-lane)
        // pf[ks] slot e holds P[q][s = ks*16 + hi*4 + (e&3) + (e>>2)*8]
        f16x8 pf[4];
#pragma unroll
        for (int ksl = 0; ksl < 2; ++ksl) {
            u32x4 w0 = {pkz(p0[8*ksl+0], p0[8*ksl+1]), pkz(p0[8*ksl+2], p0[8*ksl+3]),
                        pkz(p0[8*ksl+4], p0[8*ksl+5]), pkz(p0[8*ksl+6], p0[8*ksl+7])};
            pf[ksl] = __builtin_bit_cast(f16x8, w0);
            u32x4 w1 = {pkz(p1[8*ksl+0], p1[8*ksl+1]), pkz(p1[8*ksl+2], p1[8*ksl+3]),
                        pkz(p1[8*ksl+4], p1[8*ksl+5]), pkz(p1[8*ksl+6], p1[8*ksl+7])};
            pf[2 + ksl] = __builtin_bit_cast(f16x8, w1);
        }

        // ---- PV: O[q][d] += P[q][s] @ V[s][d]; V-frag gathered with the SAME slot map
        __builtin_amdgcn_s_setprio(1);
#pragma unroll
        for (int dt = 0; dt < 4; ++dt) {
            const f16* vrow = Vl + (dt * 32 + l31) * 68;
#pragma unroll
            for (int ks = 0; ks < 4; ++ks) {
                const f16x4 vlo = *(const f16x4*)(vrow + ks * 16 + hi4);
                const f16x4 vhi = *(const f16x4*)(vrow + ks * 16 + hi4 + 8);
                const f16x8 vf = __builtin_shufflevector(vlo, vhi, 0, 1, 2, 3, 4, 5, 6, 7);
                o[dt] = MFMA32(pf[ks], vf, o[dt]);
            }
        }
        __builtin_amdgcn_s_setprio(0);

        __syncthreads();            // all waves done READING Kl/Vl
        if (t < 31) {
            WRITET();               // overwrite single buffer with next tile
            __syncthreads();        // writes visible before next iteration's reads
        }
    }
#undef LOADT
#undef WRITET

    // ---- epilogue: normalize (1/l broadcast by q-row), write ctx [b*2048+t][h*128+d]
    const float inv = 1.0f / lrow;
    if (hi == 0) bnc[w][l31] = inv;
#pragma unroll
    for (int r = 0; r < 16; ++r) {
        const int qq = (r & 3) + 8 * (r >> 2) + 4 * hi;
        const float ir = bnc[w][qq];
        const size_t row = (size_t)(b * 2048 + qt * 128 + w * 32 + qq);
#pragma unroll
        for (int dt = 0; dt < 4; ++dt)
            Og[row * 2048 + h * 128 + dt * 32 + l31] = (f16)(o[dt][r] * ir);
    }
}

extern "C" void kernel_launch(void* const* d_in, const int* in_sizes, int n_in,
                              void* d_out, int out_size, void* d_ws, size_t ws_size,
                              hipStream_t stream) {
    const float* hs = (const float*)d_in[0];
    const float* es = (const float*)d_in[1];
    const float* Wq = (const float*)d_in[2];
    const float* Wk = (const float*)d_in[3];
    const float* Wv = (const float*)d_in[4];
    const float* Wo = (const float*)d_in[5];
    const float* cq = (const float*)d_in[6];
    const float* sq = (const float*)d_in[7];
    const float* ck = (const float*)d_in[8];
    const float* sk = (const float*)d_in[9];
    float* out = (float*)d_out;

    f16* hs16 = (f16*)d_ws;
    f16* es16 = hs16 + 8388608;
    f16* Wq16 = es16 + 8388608;
    f16* Wk16 = Wq16 + 4194304;
    f16* Wv16 = Wk16 + 4194304;
    f16* Wo16 = Wv16 + 4194304;
    f16* Q16  = Wo16 + 4194304;
    f16* K16  = Q16 + 8388608;
    f16* Vt16 = K16 + 8388608;
    f16* ctx16 = hs16;   // reuse (hs16 dead after Q-GEMM)

    const dim3 tB(256);
    cvt_all<<<dim3(16384), tB, 0, stream>>>(hs, es, Wq, Wk, Wv, Wo, hs16);

    gemm16<4><<<dim3(512), tB, 0, stream>>>(hs16, Wq16, Q16, 4096, 2048, 2048, cq, sq);
    gemm16<4><<<dim3(512), tB, 0, stream>>>(es16, Wk16, K16, 4096, 2048, 2048, ck, sk);
    gemm16<3><<<dim3(512), tB, 0, stream>>>(Wv16, es16, Vt16, 2048, 4096, 2048, nullptr, nullptr);

    attn16<<<dim3(512), tB, 0, stream>>>(Q16, K16, Vt16, ctx16);

    gemm16<2><<<dim3(512), tB, 0, stream>>>(ctx16, Wo16, out, 4096, 2048, 2048, nullptr, nullptr);
}

// Round 12
// 289.342 us; speedup vs baseline: 1.5537x; 1.5537x over previous
//
#include <hip/hip_runtime.h>
#include <cmath>

#define SCALE_F 0.088388347648318447f  // 1/sqrt(128)

typedef _Float16 f16;
typedef _Float16 f16x8 __attribute__((ext_vector_type(8)));
typedef _Float16 f16x4 __attribute__((ext_vector_type(4)));
typedef __fp16 fp16x2 __attribute__((ext_vector_type(2)));
typedef float f32x4 __attribute__((ext_vector_type(4)));
typedef float f32x16 __attribute__((ext_vector_type(16)));
typedef unsigned int u32;
typedef unsigned int u32x2 __attribute__((ext_vector_type(2)));
typedef unsigned int u32x4 __attribute__((ext_vector_type(4)));

#define MFMA16(a, b, c) __builtin_amdgcn_mfma_f32_16x16x32_f16(a, b, c, 0, 0, 0)
#define MFMA32(a, b, c) __builtin_amdgcn_mfma_f32_32x32x16_f16(a, b, c, 0, 0, 0)
#define Z16 ((f32x16){0.f,0.f,0.f,0.f,0.f,0.f,0.f,0.f,0.f,0.f,0.f,0.f,0.f,0.f,0.f,0.f})
#define EX2(x) __builtin_amdgcn_exp2f(x)

__device__ __forceinline__ void gl2lds16(const f16* g, f16* l) {
    __builtin_amdgcn_global_load_lds(
        (const __attribute__((address_space(1))) unsigned int*)g,
        (__attribute__((address_space(3))) unsigned int*)l, 16, 0, 0);
}

// packed RTZ convert: 1 instruction for 2 values (P in [0,1] -> bias ~ -0.5ulp, ok)
__device__ __forceinline__ u32 pkz(float x, float y) {
    fp16x2 h = __builtin_amdgcn_cvt_pkrtz(x, y);
    return __builtin_bit_cast(u32, h);
}
// own + partner(lane^32): explicit fresh register (=&v) so operands can't coalesce;
// symmetric combine -> correct under either permlane32_swap direction.
__device__ __forceinline__ float fswapsum(float x) {
    u32 a = __builtin_bit_cast(u32, x), b;
    asm volatile("v_mov_b32 %0, %1" : "=&v"(b) : "v"(a));
    asm volatile("v_permlane32_swap_b32 %0, %1" : "+v"(a), "+v"(b));
    return __builtin_bit_cast(float, a) + __builtin_bit_cast(float, b);
}
__device__ __forceinline__ float fswapmax(float x) {
    u32 a = __builtin_bit_cast(u32, x), b;
    asm volatile("v_mov_b32 %0, %1" : "=&v"(b) : "v"(a));
    asm volatile("v_permlane32_swap_b32 %0, %1" : "+v"(a), "+v"(b));
    return fmaxf(__builtin_bit_cast(float, a), __builtin_bit_cast(float, b));
}
#define MAX3(a, b, c) fmaxf(fmaxf((a), (b)), (c))   // fuses to v_max3_f32

// ---------------- merged f32 -> f16 convert for all 6 inputs ----------------
__global__ __launch_bounds__(256) void cvt_all(
    const float* __restrict__ hs, const float* __restrict__ es,
    const float* __restrict__ Wq, const float* __restrict__ Wk,
    const float* __restrict__ Wv, const float* __restrict__ Wo,
    f16* __restrict__ dst)
{
    const int c = blockIdx.x * 256 + threadIdx.x;   // chunk of 8 f32, 4194304 total
    const float* src; int off;
    if (c < 2097152) { src = (c < 1048576) ? hs : es; off = c & 1048575; }
    else {
        const int cc = c - 2097152;
        const int wsel = cc >> 19; off = cc & 524287;
        src = wsel == 0 ? Wq : wsel == 1 ? Wk : wsel == 2 ? Wv : Wo;
    }
    const float4* p = (const float4*)src + (size_t)off * 2;
    const float4 a = p[0], b2 = p[1];
    f16x8 o = {(f16)a.x, (f16)a.y, (f16)a.z, (f16)a.w,
               (f16)b2.x, (f16)b2.y, (f16)b2.z, (f16)b2.w};
    *(f16x8*)(dst + (size_t)c * 8) = o;
}

// ---------------- GEMM: C[M,N] = A[M,K] @ W[N,K]^T, fp16 in, MFMA ----------------
// OUT_MODE: 0 = f16 [M][N]
//           2 = f32 [M][N]
//           3 = f16 "Vt" write: out[((c>>11)*2048 + r)*2048 + (c&2047)]  (A=Wv, W=es)
//           4 = f16 [M][N] with fused RoPE (pairs along c; tables Cs/Sn [2048][64])
template <int OUT_MODE>
__global__ __launch_bounds__(256, 2) void gemm16(
    const f16* __restrict__ A, const f16* __restrict__ W,
    void* __restrict__ Cv, int M, int N, int K,
    const float* __restrict__ Cs, const float* __restrict__ Sn)
{
    __shared__ __align__(16) f16 Al[128 * 64];
    __shared__ __align__(16) f16 Bl[128 * 64];
    const int tid = threadIdx.x;
    const int l = tid & 63, w = tid >> 6;
    const int wr = w >> 1, wc = w & 1;

    const int nwg = gridDim.x, cpx = nwg >> 3;
    const int bid = blockIdx.x;
    const int swz = (bid & 7) * cpx + (bid >> 3);
    const int nbn = N >> 7;
    const int bm = (swz / nbn) * 128, bn = (swz % nbn) * 128;

    f32x4 acc[4][4];
#pragma unroll
    for (int i = 0; i < 4; ++i)
#pragma unroll
        for (int j = 0; j < 4; ++j) acc[i][j] = (f32x4){0.f, 0.f, 0.f, 0.f};

    const int srow = tid >> 3;
    const int sg = tid & 7;

    for (int k0 = 0; k0 < K; k0 += 64) {
        __syncthreads();
#pragma unroll
        for (int i = 0; i < 4; ++i) {
            const int row = i * 32 + srow;
            const int lg = sg ^ (row & 7);
            gl2lds16(A + (size_t)(bm + row) * K + k0 + lg * 8, Al + row * 64 + sg * 8);
            gl2lds16(W + (size_t)(bn + row) * K + k0 + lg * 8, Bl + row * 64 + sg * 8);
        }
        __syncthreads();
#pragma unroll
        for (int kk = 0; kk < 2; ++kk) {
            f16x8 a[4], b[4];
            const int g = kk * 4 + (l >> 4);
#pragma unroll
            for (int m = 0; m < 4; ++m) {
                const int row = wr * 64 + m * 16 + (l & 15);
                a[m] = *(const f16x8*)(Al + row * 64 + (g ^ (row & 7)) * 8);
            }
#pragma unroll
            for (int n = 0; n < 4; ++n) {
                const int row = wc * 64 + n * 16 + (l & 15);
                b[n] = *(const f16x8*)(Bl + row * 64 + (g ^ (row & 7)) * 8);
            }
#pragma unroll
            for (int m = 0; m < 4; ++m)
#pragma unroll
                for (int n = 0; n < 4; ++n)
                    acc[m][n] = MFMA16(a[m], b[n], acc[m][n]);
        }
    }

#pragma unroll
    for (int m = 0; m < 4; ++m)
#pragma unroll
        for (int n = 0; n < 4; ++n)
#pragma unroll
            for (int j = 0; j < 4; ++j) {
                const int r = bm + wr * 64 + m * 16 + ((l >> 4) << 2) + j;
                const int c = bn + wc * 64 + n * 16 + (l & 15);
                if (OUT_MODE == 0) {
                    ((f16*)Cv)[(size_t)r * N + c] = (f16)acc[m][n][j];
                } else if (OUT_MODE == 2) {
                    ((float*)Cv)[(size_t)r * N + c] = acc[m][n][j];
                } else if (OUT_MODE == 3) {
                    ((f16*)Cv)[(size_t)((c >> 11) * 2048 + r) * 2048 + (c & 2047)] = (f16)acc[m][n][j];
                } else if (OUT_MODE == 4) {
                    const float v = acc[m][n][j];
                    const float vp = __shfl_xor(v, 1);
                    const int t = r & 2047;
                    const int i2 = (c & 127) >> 1;
                    const float co = Cs[t * 64 + i2];
                    const float si = Sn[t * 64 + i2];
                    const float y = (c & 1) ? fmaf(v, co, vp * si) : fmaf(v, co, -vp * si);
                    ((f16*)Cv)[(size_t)r * N + c] = (f16)y;
                }
            }
}

// ---------------- Flash attention: 4 waves x 32 q-rows, 32x32x16 MFMA, swapped QK^T ----------------
// SINGLE-buffer padded LDS (35 KB): 4 blocks/CU comes from RESOURCES, not a VGPR cap —
// launch_bounds stays (256,2) (the (256,4) cap of round 11 forced a 64-VGPR spill disaster).
// Reg-staged K/V (T14). K pitch 132 / V pitch 68 halfs -> bank rotation -> ~2-way reads.
__global__ __launch_bounds__(256, 2) void attn16(
    const f16* __restrict__ Qg, const f16* __restrict__ Kg,
    const f16* __restrict__ Vt, f16* __restrict__ Og)
{
    __shared__ __align__(16) f16 Kl[64 * 132];   // [s][d], pitch 132 (264B)
    __shared__ __align__(16) f16 Vl[128 * 68];   // [d][s], pitch 68  (136B)
    __shared__ float bnc[4][32];                 // per-wave q-indexed broadcast

    const int tid = threadIdx.x;
    const int l = tid & 63, w = tid >> 6;           // w in 0..3
    const int l31 = l & 31, hi = l >> 5;
    const int hi4 = hi * 4;

    // staging decomposition
    const int krow = tid >> 4, kg = tid & 15;       // K: rows krow+16u, granule kg (16B)
    const int vd = tid >> 3, vg = tid & 7;          // V: d-rows vd+32u, granule vg

    // XCD swizzle: 512 blocks, 64 consecutive per XCD
    const int bid = blockIdx.x;
    const int swz = (bid & 7) * 64 + (bid >> 3);
    const int bh = swz >> 4, qt = swz & 15;
    const int b = bh >> 4, h = bh & 15;

    // Q fragments (B-operand): lane's q = l31; k = kc*16 + hi*8 + e. Scale folded (log2e).
    const int qrow = b * 2048 + qt * 128 + w * 32 + l31;
    const f16 qsc = (f16)(0.088388347648318447f * 1.44269504088896f);
    f16x8 qf[8];
#pragma unroll
    for (int kc = 0; kc < 8; ++kc) {
        f16x8 t0 = *(const f16x8*)(Qg + (size_t)qrow * 2048 + h * 128 + kc * 16 + hi * 8);
#pragma unroll
        for (int e = 0; e < 8; ++e) t0[e] = t0[e] * qsc;
        qf[kc] = t0;
    }

    f32x16 o[4] = {Z16, Z16, Z16, Z16};   // O[q=crow(r,hi)][d=dt*32+l31]
    float mrow = -3.0e38f, lrow = 0.0f;   // per-lane, q = l31 (dup across hi)

    const f16* Kbase = Kg + (size_t)(b * 2048) * 2048 + h * 128;
    const f16* Vbase = Vt + (size_t)(b * 2048 + h * 128) * 2048;

    u32x4 kst[4], vst[4];

#define LOADT(st) do {                                                                   \
    _Pragma("unroll")                                                                    \
    for (int u = 0; u < 4; ++u)                                                          \
        kst[u] = *(const u32x4*)(Kbase + (size_t)((st) + krow + u * 16) * 2048 + kg * 8);\
    _Pragma("unroll")                                                                    \
    for (int u = 0; u < 4; ++u)                                                          \
        vst[u] = *(const u32x4*)(Vbase + (size_t)(vd + u * 32) * 2048 + (st) + vg * 8);  \
} while (0)

#define WRITET() do {                                                                    \
    _Pragma("unroll")                                                                    \
    for (int u = 0; u < 4; ++u) {                                                        \
        f16* p = &Kl[(krow + u * 16) * 132 + kg * 8];                                    \
        *(u32x2*)p       = (u32x2){kst[u].x, kst[u].y};                                  \
        *(u32x2*)(p + 4) = (u32x2){kst[u].z, kst[u].w};                                  \
    }                                                                                    \
    _Pragma("unroll")                                                                    \
    for (int u = 0; u < 4; ++u) {                                                        \
        f16* p = &Vl[(vd + u * 32) * 68 + vg * 8];                                       \
        *(u32x2*)p       = (u32x2){vst[u].x, vst[u].y};                                  \
        *(u32x2*)(p + 4) = (u32x2){vst[u].z, vst[u].w};                                  \
    }                                                                                    \
} while (0)

    LOADT(0);
    WRITET();
    __syncthreads();

    for (int t = 0; t < 32; ++t) {
        if (t < 31) LOADT((t + 1) * 64);            // issue early: hides under compute

        // ---- QK^T (swapped): P^T[s][q], lane holds q=l31, s = (r&3)+8*(r>>2)+4*hi (+32 for p1)
        f32x16 p0 = Z16, p1 = Z16;
        __builtin_amdgcn_s_setprio(1);
#pragma unroll
        for (int kc = 0; kc < 8; ++kc) {
            const int go = (kc * 2 + hi) * 8;
            const f16* kp0 = Kl + l31 * 132 + go;
            const f16* kp1 = Kl + (32 + l31) * 132 + go;
            const f16x4 a0 = *(const f16x4*)kp0, a1 = *(const f16x4*)(kp0 + 4);
            const f16x4 b0 = *(const f16x4*)kp1, b1 = *(const f16x4*)(kp1 + 4);
            const f16x8 k0 = __builtin_shufflevector(a0, a1, 0, 1, 2, 3, 4, 5, 6, 7);
            const f16x8 k1 = __builtin_shufflevector(b0, b1, 0, 1, 2, 3, 4, 5, 6, 7);
            p0 = MFMA32(k0, qf[kc], p0);
            p1 = MFMA32(k1, qf[kc], p1);
        }
        __builtin_amdgcn_s_setprio(0);

        // ---- online softmax (log2 domain): max3 reduction, lane-pair combine
        float pp[32];
#pragma unroll
        for (int r = 0; r < 16; ++r) { pp[r] = p0[r]; pp[16 + r] = p1[r]; }
        float mv[11];
#pragma unroll
        for (int i = 0; i < 10; ++i) mv[i] = MAX3(pp[3 * i], pp[3 * i + 1], pp[3 * i + 2]);
        mv[10] = fmaxf(pp[30], pp[31]);
        const float n0 = MAX3(mv[0], mv[1], mv[2]);
        const float n1 = MAX3(mv[3], mv[4], mv[5]);
        const float n2 = MAX3(mv[6], mv[7], mv[8]);
        const float n3 = MAX3(mv[9], mv[10], n0);
        float mx = MAX3(n1, n2, n3);
        mx = fswapmax(mx);

        if (!__all(mx <= mrow + 8.0f)) {
            const float mn = fmaxf(mrow, mx);
            const float cr = EX2(mrow - mn);
            mrow = mn;
            lrow *= cr;
            if (hi == 0) bnc[w][l31] = cr;
#pragma unroll
            for (int r = 0; r < 16; ++r) {
                const float crr = bnc[w][(r & 3) + 8 * (r >> 2) + 4 * hi];
                o[0][r] *= crr; o[1][r] *= crr; o[2][r] *= crr; o[3][r] *= crr;
            }
        }

        // exp2 (1 v_exp_f32 each) + depth-5 sum tree
        float st16[16];
#pragma unroll
        for (int r = 0; r < 16; ++r) {
            p0[r] = EX2(p0[r] - mrow);
            p1[r] = EX2(p1[r] - mrow);
            st16[r] = p0[r] + p1[r];
        }
#pragma unroll
        for (int r = 0; r < 8; ++r) st16[r] += st16[r + 8];
#pragma unroll
        for (int r = 0; r < 4; ++r) st16[r] += st16[r + 4];
        lrow += fswapsum((st16[0] + st16[1]) + (st16[2] + st16[3]));

        // ---- pack P -> A-frags from OWN lane values only (cvt_pkrtz, no cross-lane)
        // pf[ks] slot e holds P[q][s = ks*16 + hi*4 + (e&3) + (e>>2)*8]
        f16x8 pf[4];
#pragma unroll
        for (int ksl = 0; ksl < 2; ++ksl) {
            u32x4 w0 = {pkz(p0[8*ksl+0], p0[8*ksl+1]), pkz(p0[8*ksl+2], p0[8*ksl+3]),
                        pkz(p0[8*ksl+4], p0[8*ksl+5]), pkz(p0[8*ksl+6], p0[8*ksl+7])};
            pf[ksl] = __builtin_bit_cast(f16x8, w0);
            u32x4 w1 = {pkz(p1[8*ksl+0], p1[8*ksl+1]), pkz(p1[8*ksl+2], p1[8*ksl+3]),
                        pkz(p1[8*ksl+4], p1[8*ksl+5]), pkz(p1[8*ksl+6], p1[8*ksl+7])};
            pf[2 + ksl] = __builtin_bit_cast(f16x8, w1);
        }

        // ---- PV: O[q][d] += P[q][s] @ V[s][d]; V-frag gathered with the SAME slot map
        __builtin_amdgcn_s_setprio(1);
#pragma unroll
        for (int dt = 0; dt < 4; ++dt) {
            const f16* vrow = Vl + (dt * 32 + l31) * 68;
#pragma unroll
            for (int ks = 0; ks < 4; ++ks) {
                const f16x4 vlo = *(const f16x4*)(vrow + ks * 16 + hi4);
                const f16x4 vhi = *(const f16x4*)(vrow + ks * 16 + hi4 + 8);
                const f16x8 vf = __builtin_shufflevector(vlo, vhi, 0, 1, 2, 3, 4, 5, 6, 7);
                o[dt] = MFMA32(pf[ks], vf, o[dt]);
            }
        }
        __builtin_amdgcn_s_setprio(0);

        __syncthreads();            // all waves done READING Kl/Vl
        if (t < 31) {
            WRITET();               // overwrite single buffer with next tile
            __syncthreads();        // writes visible before next iteration's reads
        }
    }
#undef LOADT
#undef WRITET

    // ---- epilogue: normalize (1/l broadcast by q-row), write ctx [b*2048+t][h*128+d]
    const float inv = 1.0f / lrow;
    if (hi == 0) bnc[w][l31] = inv;
#pragma unroll
    for (int r = 0; r < 16; ++r) {
        const int qq = (r & 3) + 8 * (r >> 2) + 4 * hi;
        const float ir = bnc[w][qq];
        const size_t row = (size_t)(b * 2048 + qt * 128 + w * 32 + qq);
#pragma unroll
        for (int dt = 0; dt < 4; ++dt)
            Og[row * 2048 + h * 128 + dt * 32 + l31] = (f16)(o[dt][r] * ir);
    }
}

extern "C" void kernel_launch(void* const* d_in, const int* in_sizes, int n_in,
                              void* d_out, int out_size, void* d_ws, size_t ws_size,
                              hipStream_t stream) {
    const float* hs = (const float*)d_in[0];
    const float* es = (const float*)d_in[1];
    const float* Wq = (const float*)d_in[2];
    const float* Wk = (const float*)d_in[3];
    const float* Wv = (const float*)d_in[4];
    const float* Wo = (const float*)d_in[5];
    const float* cq = (const float*)d_in[6];
    const float* sq = (const float*)d_in[7];
    const float* ck = (const float*)d_in[8];
    const float* sk = (const float*)d_in[9];
    float* out = (float*)d_out;

    f16* hs16 = (f16*)d_ws;
    f16* es16 = hs16 + 8388608;
    f16* Wq16 = es16 + 8388608;
    f16* Wk16 = Wq16 + 4194304;
    f16* Wv16 = Wk16 + 4194304;
    f16* Wo16 = Wv16 + 4194304;
    f16* Q16  = Wo16 + 4194304;
    f16* K16  = Q16 + 8388608;
    f16* Vt16 = K16 + 8388608;
    f16* ctx16 = hs16;   // reuse (hs16 dead after Q-GEMM)

    const dim3 tB(256);
    cvt_all<<<dim3(16384), tB, 0, stream>>>(hs, es, Wq, Wk, Wv, Wo, hs16);

    gemm16<4><<<dim3(512), tB, 0, stream>>>(hs16, Wq16, Q16, 4096, 2048, 2048, cq, sq);
    gemm16<4><<<dim3(512), tB, 0, stream>>>(es16, Wk16, K16, 4096, 2048, 2048, ck, sk);
    gemm16<3><<<dim3(512), tB, 0, stream>>>(Wv16, es16, Vt16, 2048, 4096, 2048, nullptr, nullptr);

    attn16<<<dim3(512), tB, 0, stream>>>(Q16, K16, Vt16, ctx16);

    gemm16<2><<<dim3(512), tB, 0, stream>>>(ctx16, Wo16, out, 4096, 2048, 2048, nullptr, nullptr);
}